// Round 2
// baseline (901.648 us; speedup 1.0000x reference)
//
#include <hip/hip_runtime.h>
#include <hip/hip_bf16.h>

typedef __attribute__((ext_vector_type(8))) short bf16x8;
typedef __attribute__((ext_vector_type(4))) float f32x4;
typedef unsigned short u16;
typedef unsigned int u32;

#define SEQ 2048
#define DMODEL 2048
#define NH 16
#define HD 128
#define NBATCH 2
#define WINDOW 1024

__device__ __forceinline__ float bf2f(u16 v) {
    union { u32 u; float f; } x; x.u = ((u32)v) << 16; return x.f;
}
__device__ __forceinline__ u16 f2bf(float f) {
    union { float f; u32 u; } x; x.f = f;
    u32 u = x.u;
    u32 r = (u + 0x7fffu + ((u >> 16) & 1u)) >> 16;
    return (u16)r;
}

// ---------------------------------------------------------------------------
// fp32 -> bf16 elementwise convert (8 elems/thread).
// ---------------------------------------------------------------------------
__global__ __launch_bounds__(256) void cvt_f32_bf16(
    const float* __restrict__ in, u16* __restrict__ out)
{
    long i = ((long)blockIdx.x * 256 + threadIdx.x) * 8;
    float4 a = *(const float4*)(in + i);
    float4 b = *(const float4*)(in + i + 4);
    u16 v[8] = {f2bf(a.x), f2bf(a.y), f2bf(a.z), f2bf(a.w),
                f2bf(b.x), f2bf(b.y), f2bf(b.z), f2bf(b.w)};
    *(uint4*)(out + i) = *(uint4*)v;
}

// ---------------------------------------------------------------------------
// Transpose + downcast: in fp32 (R x C) -> out bf16 (C x R). 64x64 tiles,
// padded LDS (correctness-first; these move only ~17 MB total).
// ---------------------------------------------------------------------------
__global__ __launch_bounds__(256) void transpose_f32_bf16(
    const float* __restrict__ in, u16* __restrict__ out, int R, int C)
{
    __shared__ u16 tile[64 * 72];
    const int c0 = blockIdx.x * 64, r0 = blockIdx.y * 64;
    const int t = threadIdx.x;
#pragma unroll
    for (int i = 0; i < 4; ++i) {
        int ch = i * 256 + t;
        int r = ch >> 4, c4 = (ch & 15) * 4;
        float4 v = *(const float4*)(in + (long)(r0 + r) * C + c0 + c4);
        tile[r * 72 + c4 + 0] = f2bf(v.x);
        tile[r * 72 + c4 + 1] = f2bf(v.y);
        tile[r * 72 + c4 + 2] = f2bf(v.z);
        tile[r * 72 + c4 + 3] = f2bf(v.w);
    }
    __syncthreads();
#pragma unroll
    for (int i = 0; i < 4; ++i) {
        int ch = i * 256 + t;
        int oc = ch >> 4, sg = (ch & 15) * 4;   // out row = in col oc; cols = in rows sg..sg+3
        u16 vals[4];
#pragma unroll
        for (int j = 0; j < 4; ++j) vals[j] = tile[(sg + j) * 72 + oc];
        *(uint2*)(out + (long)(c0 + oc) * R + r0 + sg) = *(uint2*)vals;
    }
}

// ---------------------------------------------------------------------------
// GEMM: C[M x 2048] = A[M x 2048] @ Bt^T, A bf16, Bt bf16 (N x K) row-major.
// 128x128 tile, BK=64, 4 waves (2x2 of 64x64), mfma 16x16x32 bf16.
// MODE 0: fp32 row-major C to OutF.
// MODE 1: QKV epilogue: z in {0,1,2} selects weight/output; z<2 applies RoPE
//         (fp32 cos/sin tables); z<2 scatters to (b,h,s,d); z==2 scatters V
//         directly transposed to (b,h,d,s) for attention.
// ---------------------------------------------------------------------------
template <int MODE>
__global__ __launch_bounds__(256, 2) void gemm_bt(
    const u16* __restrict__ A, const u16* __restrict__ Bt,
    u16* __restrict__ OutB, float* __restrict__ OutF,
    const float* __restrict__ cosb, const float* __restrict__ sinb)
{
    __shared__ u16 a_lds[128 * 72];
    __shared__ u16 b_lds[128 * 72];
    const int t = threadIdx.x;
    const int w = t >> 6, l = t & 63;
    const int g = l >> 4, l15 = l & 15;
    const int wr = w >> 1, wc = w & 1;
    const int m0 = blockIdx.y * 128, n0 = blockIdx.x * 128;
    const int z = blockIdx.z;
    const u16* Abase = A + (long)m0 * 2048;
    const u16* Bbase = Bt + (long)z * 2048 * 2048 + (long)n0 * 2048;

    f32x4 acc[4][4] = {};
    uint4 ra[4], rb[4];

#pragma unroll
    for (int i = 0; i < 4; ++i) {
        int ch = i * 256 + t; int r = ch >> 3, c = (ch & 7) * 8;
        ra[i] = *(const uint4*)(Abase + (long)r * 2048 + c);
        rb[i] = *(const uint4*)(Bbase + (long)r * 2048 + c);
    }
    for (int kt = 0; kt < 32; ++kt) {
#pragma unroll
        for (int i = 0; i < 4; ++i) {
            int ch = i * 256 + t; int r = ch >> 3, c = (ch & 7) * 8;
            *(uint4*)(a_lds + r * 72 + c) = ra[i];
            *(uint4*)(b_lds + r * 72 + c) = rb[i];
        }
        __syncthreads();
        if (kt + 1 < 32) {
            int k0 = (kt + 1) * 64;
#pragma unroll
            for (int i = 0; i < 4; ++i) {
                int ch = i * 256 + t; int r = ch >> 3, c = (ch & 7) * 8;
                ra[i] = *(const uint4*)(Abase + (long)r * 2048 + k0 + c);
                rb[i] = *(const uint4*)(Bbase + (long)r * 2048 + k0 + c);
            }
        }
#pragma unroll
        for (int kk = 0; kk < 2; ++kk) {
            bf16x8 af[4], bfr[4];
#pragma unroll
            for (int mt = 0; mt < 4; ++mt)
                af[mt] = *(const bf16x8*)(a_lds + (wr * 64 + mt * 16 + l15) * 72 + kk * 32 + g * 8);
#pragma unroll
            for (int nt = 0; nt < 4; ++nt)
                bfr[nt] = *(const bf16x8*)(b_lds + (wc * 64 + nt * 16 + l15) * 72 + kk * 32 + g * 8);
#pragma unroll
            for (int mt = 0; mt < 4; ++mt)
#pragma unroll
                for (int nt = 0; nt < 4; ++nt)
                    acc[mt][nt] = __builtin_amdgcn_mfma_f32_16x16x32_bf16(af[mt], bfr[nt], acc[mt][nt], 0, 0, 0);
        }
        __syncthreads();
    }

    // epilogue: C[row][col]: col = lane&15, row = (lane>>4)*4 + reg  [m89]
#pragma unroll
    for (int mt = 0; mt < 4; ++mt) {
#pragma unroll
        for (int nt = 0; nt < 4; ++nt) {
#pragma unroll
            for (int r = 0; r < 4; ++r) {
                int m = m0 + wr * 64 + mt * 16 + g * 4 + r;
                int n = n0 + wc * 64 + nt * 16 + l15;
                float v = acc[mt][nt][r];
                if (MODE == 0) {
                    OutF[(long)m * 2048 + n] = v;
                } else {
                    int b = m >> 11, s = m & 2047;
                    int h = n >> 7,  d = n & 127;
                    float pv = __shfl_xor(v, 1);
                    if (z < 2) {
                        int p = d >> 1;
                        float cc = cosb[s * 64 + p];
                        float ss = sinb[s * 64 + p];
                        v = ((d & 1) == 0) ? (v * cc - pv * ss) : (pv * ss + v * cc);
                    }
                    long zoff = (long)z * (NBATCH * NH * SEQ * HD);
                    if (z == 2)
                        OutB[zoff + ((long)(b * NH + h) * HD + d) * SEQ + s] = f2bf(v);
                    else
                        OutB[zoff + ((long)(b * NH + h) * SEQ + s) * HD + d] = f2bf(v);
                }
            }
        }
    }
}

// ---------------------------------------------------------------------------
// Flash attention with sliding window. grid = (S/64 q-tiles, B*H).
// Block = 4 waves; wave w owns q rows [q0+16w, q0+16w+16). KV tiles of 64.
// K staged (s,d); V staged from pre-transposed (d,s).
// Online softmax: masked = -1e30; the first real tile's rescale factor
// underflows to 0, erasing any fully-masked-tile pollution.
// ---------------------------------------------------------------------------
__global__ __launch_bounds__(256, 2) void attn_kernel(
    const u16* __restrict__ Q,   // (B*H, S, HD)
    const u16* __restrict__ K,   // (B*H, S, HD)
    const u16* __restrict__ Vt,  // (B*H, HD, S)
    u16* __restrict__ Out)       // (B, S, D_MODEL)
{
    __shared__ u16 k_lds[64 * 136];
    __shared__ u16 vt_lds[128 * 72];
    __shared__ u16 p_lds[4 * 16 * 72];
    const int t = threadIdx.x, w = t >> 6, l = t & 63;
    const int g = l >> 4, l15 = l & 15;
    const int q0 = blockIdx.x * 64;
    const int bh = blockIdx.y;
    const int qbase = q0 + w * 16;
    const u16* Qb = Q + (long)bh * SEQ * HD;
    const u16* Kb = K + (long)bh * SEQ * HD;
    const u16* Vb = Vt + (long)bh * HD * SEQ;
    u16* pw = p_lds + w * 16 * 72;

    bf16x8 qf[4];
#pragma unroll
    for (int kk = 0; kk < 4; ++kk)
        qf[kk] = *(const bf16x8*)(Qb + (long)(qbase + l15) * HD + kk * 32 + g * 8);

    f32x4 of[8] = {};
    float mrow[4] = {-1e30f, -1e30f, -1e30f, -1e30f};
    float lrow[4] = {0.f, 0.f, 0.f, 0.f};
    const float scale = 0.088388347648318447f; // 1/sqrt(128)

    const int t0 = (q0 >= WINDOW) ? ((q0 - (WINDOW - 1)) >> 6) : 0;
    const int t1 = q0 >> 6;

    for (int kt = t0; kt <= t1; ++kt) {
        const int kv0 = kt * 64;
#pragma unroll
        for (int i = 0; i < 4; ++i) {
            int ch = i * 256 + t;
            { int r = ch >> 4, c = (ch & 15) * 8;
              *(uint4*)(k_lds + r * 136 + c) = *(const uint4*)(Kb + (long)(kv0 + r) * HD + c); }
            { int r = ch >> 3, c = (ch & 7) * 8;
              *(uint4*)(vt_lds + r * 72 + c) = *(const uint4*)(Vb + (long)r * SEQ + kv0 + c); }
        }
        __syncthreads();

        // S = Q K^T  (C[q-row][kv-col])
        f32x4 sf[4] = {};
#pragma unroll
        for (int kk = 0; kk < 4; ++kk) {
#pragma unroll
            for (int nt = 0; nt < 4; ++nt) {
                bf16x8 kf = *(const bf16x8*)(k_lds + (nt * 16 + l15) * 136 + kk * 32 + g * 8);
                sf[nt] = __builtin_amdgcn_mfma_f32_16x16x32_bf16(qf[kk], kf, sf[nt], 0, 0, 0);
            }
        }
        const bool full = (kv0 + 63 <= qbase) && ((qbase + 15) - kv0 < WINDOW);
#pragma unroll
        for (int nt = 0; nt < 4; ++nt)
#pragma unroll
            for (int r = 0; r < 4; ++r) {
                float s = sf[nt][r] * scale;
                if (!full) {
                    int q = qbase + g * 4 + r;
                    int kv = kv0 + nt * 16 + l15;
                    bool ok = (kv <= q) && (q - kv < WINDOW);
                    s = ok ? s : -1e30f;
                }
                sf[nt][r] = s;
            }
        float fr[4];
#pragma unroll
        for (int r = 0; r < 4; ++r) {
            float v = fmaxf(fmaxf(sf[0][r], sf[1][r]), fmaxf(sf[2][r], sf[3][r]));
            v = fmaxf(v, __shfl_xor(v, 1));
            v = fmaxf(v, __shfl_xor(v, 2));
            v = fmaxf(v, __shfl_xor(v, 4));
            v = fmaxf(v, __shfl_xor(v, 8));
            float mn = fmaxf(mrow[r], v);
            fr[r] = __expf(mrow[r] - mn);
            mrow[r] = mn;
        }
        float rs[4] = {0.f, 0.f, 0.f, 0.f};
#pragma unroll
        for (int nt = 0; nt < 4; ++nt)
#pragma unroll
            for (int r = 0; r < 4; ++r) {
                float p = __expf(sf[nt][r] - mrow[r]);
                rs[r] += p;
                pw[(g * 4 + r) * 72 + nt * 16 + l15] = f2bf(p);
            }
#pragma unroll
        for (int r = 0; r < 4; ++r) {
            float v = rs[r];
            v += __shfl_xor(v, 1);
            v += __shfl_xor(v, 2);
            v += __shfl_xor(v, 4);
            v += __shfl_xor(v, 8);
            lrow[r] = lrow[r] * fr[r] + v;
        }
#pragma unroll
        for (int nd = 0; nd < 8; ++nd)
#pragma unroll
            for (int r = 0; r < 4; ++r) of[nd][r] *= fr[r];
#pragma unroll
        for (int kk = 0; kk < 2; ++kk) {
            bf16x8 pa = *(const bf16x8*)(pw + l15 * 72 + kk * 32 + g * 8);
#pragma unroll
            for (int nd = 0; nd < 8; ++nd) {
                bf16x8 vb = *(const bf16x8*)(vt_lds + (nd * 16 + l15) * 72 + kk * 32 + g * 8);
                of[nd] = __builtin_amdgcn_mfma_f32_16x16x32_bf16(pa, vb, of[nd], 0, 0, 0);
            }
        }
        __syncthreads();
    }
    const int b = bh >> 4, h = bh & 15;
#pragma unroll
    for (int r = 0; r < 4; ++r) {
        float inv = 1.0f / lrow[r];
        int q = qbase + g * 4 + r;
        u16* orow = Out + ((long)(b * SEQ + q)) * DMODEL + h * HD;
#pragma unroll
        for (int nd = 0; nd < 8; ++nd)
            orow[nd * 16 + l15] = f2bf(of[nd][r] * inv);
    }
}

// ---------------------------------------------------------------------------
extern "C" void kernel_launch(void* const* d_in, const int* in_sizes, int n_in,
                              void* d_out, int out_size, void* d_ws, size_t ws_size,
                              hipStream_t stream) {
    (void)in_sizes; (void)n_in; (void)out_size; (void)ws_size;
    const float* x    = (const float*)d_in[0];
    const float* fcos = (const float*)d_in[1];
    const float* fsin = (const float*)d_in[2];
    // d_in[3] = dense mask, unused (masking computed analytically)
    const float* wq = (const float*)d_in[4];
    const float* wk = (const float*)d_in[5];
    const float* wv = (const float*)d_in[6];
    const float* wo = (const float*)d_in[7];

    u16* ws = (u16*)d_ws;
    const long WT = 2048L * 2048;        // 4194304 elements per weight
    u16* xb  = ws;                        // 8388608
    u16* wtq = xb + 8388608L;
    u16* wtk = wtq + WT;
    u16* wtv = wtk + WT;
    u16* wto = wtv + WT;
    u16* qkv = wto + WT;                  // 3 x 8388608 (q:(b,h,s,d), k:(b,h,s,d), v:(b,h,d,s))
    u16* q_ws = qkv;
    u16* k_ws = qkv + 8388608L;
    u16* vt_ws = qkv + 16777216L;
    u16* attn_ws = qkv + 25165824L;       // 8388608

    dim3 blk(256);
    // 1. convert x to bf16
    cvt_f32_bf16<<<4096, blk, 0, stream>>>(x, xb);
    // 2. transpose+downcast weights (K,N) -> (N,K) bf16
    transpose_f32_bf16<<<dim3(32, 32), blk, 0, stream>>>(wq, wtq, 2048, 2048);
    transpose_f32_bf16<<<dim3(32, 32), blk, 0, stream>>>(wk, wtk, 2048, 2048);
    transpose_f32_bf16<<<dim3(32, 32), blk, 0, stream>>>(wv, wtv, 2048, 2048);
    transpose_f32_bf16<<<dim3(32, 32), blk, 0, stream>>>(wo, wto, 2048, 2048);
    // 3. QKV GEMM + RoPE; q,k -> (b,h,s,d); v -> (b,h,d,s)
    gemm_bt<1><<<dim3(16, 32, 3), blk, 0, stream>>>(xb, wtq, qkv, nullptr, fcos, fsin);
    // 4. flash attention -> (b, s, h*hd) bf16
    attn_kernel<<<dim3(32, 32), blk, 0, stream>>>(q_ws, k_ws, vt_ws, attn_ws);
    // 5. out projection -> fp32 d_out
    gemm_bt<0><<<dim3(16, 32, 1), blk, 0, stream>>>(attn_ws, wto, nullptr, (float*)d_out,
                                                    nullptr, nullptr);
}

// Round 4
// 498.730 us; speedup vs baseline: 1.8079x; 1.8079x over previous
//
#include <hip/hip_runtime.h>
#include <hip/hip_bf16.h>

typedef __attribute__((ext_vector_type(8))) short bf16x8;
typedef __attribute__((ext_vector_type(4))) float f32x4;
typedef unsigned short u16;
typedef unsigned int u32;

#define SEQ 2048
#define DMODEL 2048
#define NH 16
#define HD 128
#define NBATCH 2
#define WINDOW 1024

__device__ __forceinline__ float bf2f(u16 v) {
    union { u32 u; float f; } x; x.u = ((u32)v) << 16; return x.f;
}
__device__ __forceinline__ u16 f2bf(float f) {
    union { float f; u32 u; } x; x.f = f;
    u32 u = x.u;
    u32 r = (u + 0x7fffu + ((u >> 16) & 1u)) >> 16;
    return (u16)r;
}

// ---------------------------------------------------------------------------
// fp32 -> bf16 elementwise convert (8 elems/thread).
// ---------------------------------------------------------------------------
__global__ __launch_bounds__(256) void cvt_f32_bf16(
    const float* __restrict__ in, u16* __restrict__ out)
{
    long i = ((long)blockIdx.x * 256 + threadIdx.x) * 8;
    float4 a = *(const float4*)(in + i);
    float4 b = *(const float4*)(in + i + 4);
    u16 v[8] = {f2bf(a.x), f2bf(a.y), f2bf(a.z), f2bf(a.w),
                f2bf(b.x), f2bf(b.y), f2bf(b.z), f2bf(b.w)};
    *(uint4*)(out + i) = *(uint4*)v;
}

// ---------------------------------------------------------------------------
// Transpose + downcast: in fp32 (R x C) -> out bf16 (C x R). 64x64 tiles.
// ---------------------------------------------------------------------------
__global__ __launch_bounds__(256) void transpose_f32_bf16(
    const float* __restrict__ in, u16* __restrict__ out, int R, int C)
{
    __shared__ u16 tile[64 * 72];
    const int c0 = blockIdx.x * 64, r0 = blockIdx.y * 64;
    const int t = threadIdx.x;
#pragma unroll
    for (int i = 0; i < 4; ++i) {
        int ch = i * 256 + t;
        int r = ch >> 4, c4 = (ch & 15) * 4;
        float4 v = *(const float4*)(in + (long)(r0 + r) * C + c0 + c4);
        tile[r * 72 + c4 + 0] = f2bf(v.x);
        tile[r * 72 + c4 + 1] = f2bf(v.y);
        tile[r * 72 + c4 + 2] = f2bf(v.z);
        tile[r * 72 + c4 + 3] = f2bf(v.w);
    }
    __syncthreads();
#pragma unroll
    for (int i = 0; i < 4; ++i) {
        int ch = i * 256 + t;
        int oc = ch >> 4, sg = (ch & 15) * 4;
        u16 vals[4];
#pragma unroll
        for (int j = 0; j < 4; ++j) vals[j] = tile[(sg + j) * 72 + oc];
        *(uint2*)(out + (long)(c0 + oc) * R + r0 + sg) = *(uint2*)vals;
    }
}

// ---------------------------------------------------------------------------
// 256x256-tile 8-wave GEMM, BK=64, mfma 16x16x32 bf16, 4-phase/K-tile
// counted-vmcnt schedule (T1 XCD swizzle + T2 LDS swizzle + T3/T4 + T5).
// C[M x 2048] = A[M x 2048] @ Bt^T, Bt (N x K) row-major bf16.
// LDS (dynamic, 128 KiB): A: 2 bufs x 2 halves(128 rows) x [128x64];
//                         B: 2 bufs x 2 slots(n-quadrant rows) x [128x64].
// Staging: global_load_lds 16B, linear LDS dest, inverse-swizzled global src.
// Reads: ds_read_b128 with byte ^= ((row&7)<<4) (elements: ^ (l15&7)<<3).
// Waits: vmcnt(2) at phases 1 and 4 only (before a barrier). Never 0 in loop.
// MODE 0: fp32 row-major C. MODE 1: QKV epilogue (RoPE z<2, scatter; z==2
// writes V transposed (b,h,d,s)).
// ---------------------------------------------------------------------------
#define GLD16(gp, lp) __builtin_amdgcn_global_load_lds( \
    (const __attribute__((address_space(1))) u32*)(gp), \
    (__attribute__((address_space(3))) u32*)(lp), 16, 0, 0)
#define BAR() __builtin_amdgcn_s_barrier()
#define WAITV(n) asm volatile("s_waitcnt vmcnt(" #n ")" ::: "memory")

template <int MODE>
__global__ __launch_bounds__(512, 2) void gemm256(
    const u16* __restrict__ A, const u16* __restrict__ Bt,
    u16* __restrict__ OutB, float* __restrict__ OutF,
    const float* __restrict__ cosb, const float* __restrict__ sinb)
{
    extern __shared__ u16 sm[];   // [0,32768): A slots; [32768,65536): B slots
    const int t = threadIdx.x;
    const int w = t >> 6, l = t & 63;
    const int g = l >> 4, l15 = l & 15;
    const int wr = w >> 2, wc = w & 3;           // 2 x 4 wave grid

    const int NWG = (MODE == 1) ? 384 : 128;
    const int cpx = NWG / 8;                      // bijective XCD swizzle
    int bid = blockIdx.x;
    int wg = (bid & 7) * cpx + (bid >> 3);
    int z, m_t, n_t;
    if (MODE == 1) { z = wg >> 7; int rem = wg & 127; n_t = rem >> 4; m_t = rem & 15; }
    else           { z = 0; n_t = wg >> 4; m_t = wg & 15; }
    const int m0 = m_t * 256, n0 = n_t * 256;
    const u16* Ab = A + (long)m0 * 2048;
    const u16* Bb = Bt + (long)z * (2048L * 2048) + (long)n0 * 2048;

    // staging per-thread constants: thread t covers 16B chunk t (instr0) and
    // t+512 (instr1) of each 128x64 half-tile. row = chunk>>3, pk = chunk&7,
    // logical k16 = pk ^ (row&7)  (inverse swizzle on the global source).
    const int lrow0 = t >> 3;                      // 0..63 (instr1: +64)
    const int kk16  = (t & 7) ^ (lrow0 & 7);       // same for instr1 (64|row)
    const long a_g0 = (long)lrow0 * 2048 + kk16 * 8;
    const long b_g0 = (long)(((lrow0 >> 5) << 6) + (lrow0 & 31)) * 2048 + kk16 * 8;
    const int lds_w = w * 512;                     // wave-uniform elem offset
    const int sw    = (l15 & 7) << 3;              // read-side swizzle (elems)

#define STAGE_A(h, kt1) do { int _b = (kt1) & 1; \
    const u16* _gp = Ab + (long)(h) * (128 * 2048) + (long)(kt1) * 64 + a_g0; \
    u16* _lp = sm + (_b * 2 + (h)) * 8192 + lds_w; \
    GLD16(_gp, _lp); GLD16(_gp + 64 * 2048, _lp + 4096); } while (0)

#define STAGE_B(s, kt1) do { int _b = (kt1) & 1; \
    const u16* _gp = Bb + (long)(s) * (32 * 2048) + (long)(kt1) * 64 + b_g0; \
    u16* _lp = sm + 32768 + (_b * 2 + (s)) * 8192 + lds_w; \
    GLD16(_gp, _lp); GLD16(_gp + 128 * 2048, _lp + 4096); } while (0)

    bf16x8 af[4][2], bfr[2][2];
    f32x4 acc[8][4] = {};

#define LDA(mh, buf) { const u16* _ba = sm + ((buf) * 2 + wr) * 8192; \
    _Pragma("unroll") for (int i = 0; i < 4; ++i) { \
        int row = (mh) * 64 + i * 16 + l15; \
        _Pragma("unroll") for (int kx = 0; kx < 2; ++kx) \
            af[i][kx] = *(const bf16x8*)(_ba + row * 64 + ((kx * 32 + g * 8) ^ sw)); } }

#define LDB(q, buf) { const u16* _bb = sm + 32768 + ((buf) * 2 + (q)) * 8192; \
    _Pragma("unroll") for (int j = 0; j < 2; ++j) { \
        int row = wc * 32 + j * 16 + l15; \
        _Pragma("unroll") for (int kx = 0; kx < 2; ++kx) \
            bfr[j][kx] = *(const bf16x8*)(_bb + row * 64 + ((kx * 32 + g * 8) ^ sw)); } }

#define MM(mh, q) { __builtin_amdgcn_s_setprio(1); \
    _Pragma("unroll") for (int i = 0; i < 4; ++i) \
    _Pragma("unroll") for (int j = 0; j < 2; ++j) \
    _Pragma("unroll") for (int kx = 0; kx < 2; ++kx) \
        acc[(mh) * 4 + i][(q) * 2 + j] = __builtin_amdgcn_mfma_f32_16x16x32_bf16( \
            af[i][kx], bfr[j][kx], acc[(mh) * 4 + i][(q) * 2 + j], 0, 0, 0); \
    __builtin_amdgcn_s_setprio(0); }

    // prologue: stage tile 0 (order A.h0, A.h1, B.s0, B.s1)
    STAGE_A(0, 0); STAGE_A(1, 0); STAGE_B(0, 0); STAGE_B(1, 0);
    WAITV(2); BAR();

#pragma unroll 1
    for (int kt = 0; kt < 32; ++kt) {
        const int buf = kt & 1;
        const bool pf = (kt + 1 < 32);
        // P1: quad (m-half 0, n-quad 0)
        LDA(0, buf); LDB(0, buf);
        if (pf) { STAGE_A(0, kt + 1); WAITV(2); } else { WAITV(0); }
        BAR(); MM(0, 0); BAR();
        // P2: quad (0, 1)
        LDB(1, buf);
        if (pf) STAGE_A(1, kt + 1);
        BAR(); MM(0, 1); BAR();
        // P3: quad (1, 1)
        LDA(1, buf);
        if (pf) STAGE_B(0, kt + 1);
        BAR(); MM(1, 1); BAR();
        // P4: quad (1, 0)
        LDB(0, buf);
        if (pf) { STAGE_B(1, kt + 1); WAITV(2); }
        BAR(); MM(1, 0); BAR();
    }

    // epilogue: C[row][col]: col = lane&15, row = (lane>>4)*4 + reg  [m89]
#pragma unroll
    for (int mt = 0; mt < 8; ++mt) {
#pragma unroll
        for (int nt = 0; nt < 4; ++nt) {
#pragma unroll
            for (int r = 0; r < 4; ++r) {
                int m = m0 + wr * 128 + mt * 16 + g * 4 + r;
                int n = n0 + wc * 64 + nt * 16 + l15;
                float v = acc[mt][nt][r];
                if (MODE == 0) {
                    OutF[(long)m * 2048 + n] = v;
                } else {
                    int b = m >> 11, s = m & 2047;
                    int h = n >> 7,  d = n & 127;
                    float pv = __shfl_xor(v, 1);
                    if (z < 2) {
                        int p = d >> 1;
                        float cc = cosb[s * 64 + p];
                        float ss = sinb[s * 64 + p];
                        v = ((d & 1) == 0) ? (v * cc - pv * ss) : (pv * ss + v * cc);
                    }
                    long zoff = (long)z * (NBATCH * NH * SEQ * HD);
                    if (z == 2)
                        OutB[zoff + ((long)(b * NH + h) * HD + d) * SEQ + s] = f2bf(v);
                    else
                        OutB[zoff + ((long)(b * NH + h) * SEQ + s) * HD + d] = f2bf(v);
                }
            }
        }
    }
#undef STAGE_A
#undef STAGE_B
#undef LDA
#undef LDB
#undef MM
}

// ---------------------------------------------------------------------------
// Flash attention with sliding window (unchanged from passing round).
// ---------------------------------------------------------------------------
__global__ __launch_bounds__(256, 2) void attn_kernel(
    const u16* __restrict__ Q,   // (B*H, S, HD)
    const u16* __restrict__ K,   // (B*H, S, HD)
    const u16* __restrict__ Vt,  // (B*H, HD, S)
    u16* __restrict__ Out)       // (B, S, D_MODEL)
{
    __shared__ u16 k_lds[64 * 136];
    __shared__ u16 vt_lds[128 * 72];
    __shared__ u16 p_lds[4 * 16 * 72];
    const int t = threadIdx.x, w = t >> 6, l = t & 63;
    const int g = l >> 4, l15 = l & 15;
    const int q0 = blockIdx.x * 64;
    const int bh = blockIdx.y;
    const int qbase = q0 + w * 16;
    const u16* Qb = Q + (long)bh * SEQ * HD;
    const u16* Kb = K + (long)bh * SEQ * HD;
    const u16* Vb = Vt + (long)bh * HD * SEQ;
    u16* pw = p_lds + w * 16 * 72;

    bf16x8 qf[4];
#pragma unroll
    for (int kk = 0; kk < 4; ++kk)
        qf[kk] = *(const bf16x8*)(Qb + (long)(qbase + l15) * HD + kk * 32 + g * 8);

    f32x4 of[8] = {};
    float mrow[4] = {-1e30f, -1e30f, -1e30f, -1e30f};
    float lrow[4] = {0.f, 0.f, 0.f, 0.f};
    const float scale = 0.088388347648318447f; // 1/sqrt(128)

    const int t0 = (q0 >= WINDOW) ? ((q0 - (WINDOW - 1)) >> 6) : 0;
    const int t1 = q0 >> 6;

    for (int kt = t0; kt <= t1; ++kt) {
        const int kv0 = kt * 64;
#pragma unroll
        for (int i = 0; i < 4; ++i) {
            int ch = i * 256 + t;
            { int r = ch >> 4, c = (ch & 15) * 8;
              *(uint4*)(k_lds + r * 136 + c) = *(const uint4*)(Kb + (long)(kv0 + r) * HD + c); }
            { int r = ch >> 3, c = (ch & 7) * 8;
              *(uint4*)(vt_lds + r * 72 + c) = *(const uint4*)(Vb + (long)r * SEQ + kv0 + c); }
        }
        __syncthreads();

        f32x4 sf[4] = {};
#pragma unroll
        for (int kk = 0; kk < 4; ++kk) {
#pragma unroll
            for (int nt = 0; nt < 4; ++nt) {
                bf16x8 kf = *(const bf16x8*)(k_lds + (nt * 16 + l15) * 136 + kk * 32 + g * 8);
                sf[nt] = __builtin_amdgcn_mfma_f32_16x16x32_bf16(qf[kk], kf, sf[nt], 0, 0, 0);
            }
        }
        const bool full = (kv0 + 63 <= qbase) && ((qbase + 15) - kv0 < WINDOW);
#pragma unroll
        for (int nt = 0; nt < 4; ++nt)
#pragma unroll
            for (int r = 0; r < 4; ++r) {
                float s = sf[nt][r] * scale;
                if (!full) {
                    int q = qbase + g * 4 + r;
                    int kv = kv0 + nt * 16 + l15;
                    bool ok = (kv <= q) && (q - kv < WINDOW);
                    s = ok ? s : -1e30f;
                }
                sf[nt][r] = s;
            }
        float fr[4];
#pragma unroll
        for (int r = 0; r < 4; ++r) {
            float v = fmaxf(fmaxf(sf[0][r], sf[1][r]), fmaxf(sf[2][r], sf[3][r]));
            v = fmaxf(v, __shfl_xor(v, 1));
            v = fmaxf(v, __shfl_xor(v, 2));
            v = fmaxf(v, __shfl_xor(v, 4));
            v = fmaxf(v, __shfl_xor(v, 8));
            float mn = fmaxf(mrow[r], v);
            fr[r] = __expf(mrow[r] - mn);
            mrow[r] = mn;
        }
        float rs[4] = {0.f, 0.f, 0.f, 0.f};
#pragma unroll
        for (int nt = 0; nt < 4; ++nt)
#pragma unroll
            for (int r = 0; r < 4; ++r) {
                float p = __expf(sf[nt][r] - mrow[r]);
                rs[r] += p;
                pw[(g * 4 + r) * 72 + nt * 16 + l15] = f2bf(p);
            }
#pragma unroll
        for (int r = 0; r < 4; ++r) {
            float v = rs[r];
            v += __shfl_xor(v, 1);
            v += __shfl_xor(v, 2);
            v += __shfl_xor(v, 4);
            v += __shfl_xor(v, 8);
            lrow[r] = lrow[r] * fr[r] + v;
        }
#pragma unroll
        for (int nd = 0; nd < 8; ++nd)
#pragma unroll
            for (int r = 0; r < 4; ++r) of[nd][r] *= fr[r];
#pragma unroll
        for (int kk = 0; kk < 2; ++kk) {
            bf16x8 pa = *(const bf16x8*)(pw + l15 * 72 + kk * 32 + g * 8);
#pragma unroll
            for (int nd = 0; nd < 8; ++nd) {
                bf16x8 vb = *(const bf16x8*)(vt_lds + (nd * 16 + l15) * 72 + kk * 32 + g * 8);
                of[nd] = __builtin_amdgcn_mfma_f32_16x16x32_bf16(pa, vb, of[nd], 0, 0, 0);
            }
        }
        __syncthreads();
    }
    const int b = bh >> 4, h = bh & 15;
#pragma unroll
    for (int r = 0; r < 4; ++r) {
        float inv = 1.0f / lrow[r];
        int q = qbase + g * 4 + r;
        u16* orow = Out + ((long)(b * SEQ + q)) * DMODEL + h * HD;
#pragma unroll
        for (int nd = 0; nd < 8; ++nd)
            orow[nd * 16 + l15] = f2bf(of[nd][r] * inv);
    }
}

// ---------------------------------------------------------------------------
extern "C" void kernel_launch(void* const* d_in, const int* in_sizes, int n_in,
                              void* d_out, int out_size, void* d_ws, size_t ws_size,
                              hipStream_t stream) {
    (void)in_sizes; (void)n_in; (void)out_size; (void)ws_size;
    const float* x    = (const float*)d_in[0];
    const float* fcos = (const float*)d_in[1];
    const float* fsin = (const float*)d_in[2];
    // d_in[3] = dense mask, unused (masking computed analytically)
    const float* wq = (const float*)d_in[4];
    const float* wk = (const float*)d_in[5];
    const float* wv = (const float*)d_in[6];
    const float* wo = (const float*)d_in[7];

    u16* ws = (u16*)d_ws;
    const long WT = 2048L * 2048;
    u16* xb  = ws;                        // 8388608
    u16* wtq = xb + 8388608L;
    u16* wtk = wtq + WT;
    u16* wtv = wtk + WT;
    u16* wto = wtv + WT;
    u16* qkv = wto + WT;                  // q:(b,h,s,d), k:(b,h,s,d), v:(b,h,d,s)
    u16* q_ws = qkv;
    u16* k_ws = qkv + 8388608L;
    u16* vt_ws = qkv + 16777216L;
    u16* attn_ws = qkv + 25165824L;

    hipFuncSetAttribute(reinterpret_cast<const void*>(gemm256<1>),
                        hipFuncAttributeMaxDynamicSharedMemorySize, 131072);
    hipFuncSetAttribute(reinterpret_cast<const void*>(gemm256<0>),
                        hipFuncAttributeMaxDynamicSharedMemorySize, 131072);

    dim3 blk(256);
    cvt_f32_bf16<<<4096, blk, 0, stream>>>(x, xb);
    transpose_f32_bf16<<<dim3(32, 32), blk, 0, stream>>>(wq, wtq, 2048, 2048);
    transpose_f32_bf16<<<dim3(32, 32), blk, 0, stream>>>(wk, wtk, 2048, 2048);
    transpose_f32_bf16<<<dim3(32, 32), blk, 0, stream>>>(wv, wtv, 2048, 2048);
    transpose_f32_bf16<<<dim3(32, 32), blk, 0, stream>>>(wo, wto, 2048, 2048);
    // QKV GEMM + RoPE; q,k -> (b,h,s,d); v -> (b,h,d,s)
    gemm256<1><<<384, 512, 131072, stream>>>(xb, wtq, qkv, nullptr, fcos, fsin);
    // flash attention -> (b, s, h*hd) bf16
    attn_kernel<<<dim3(32, 32), blk, 0, stream>>>(q_ws, k_ws, vt_ws, attn_ws);
    // out projection -> fp32 d_out
    gemm256<0><<<128, 512, 131072, stream>>>(attn_ws, wto, nullptr, (float*)d_out,
                                             nullptr, nullptr);
}

// Round 5
// 449.597 us; speedup vs baseline: 2.0055x; 1.1093x over previous
//
#include <hip/hip_runtime.h>
#include <hip/hip_bf16.h>

typedef __attribute__((ext_vector_type(8))) short bf16x8;
typedef __attribute__((ext_vector_type(4))) float f32x4;
typedef unsigned short u16;
typedef unsigned int u32;

#define SEQ 2048
#define DMODEL 2048
#define NH 16
#define HD 128
#define NBATCH 2
#define WINDOW 1024

__device__ __forceinline__ float bf2f(u16 v) {
    union { u32 u; float f; } x; x.u = ((u32)v) << 16; return x.f;
}
__device__ __forceinline__ u16 f2bf(float f) {
    union { float f; u32 u; } x; x.f = f;
    u32 u = x.u;
    u32 r = (u + 0x7fffu + ((u >> 16) & 1u)) >> 16;
    return (u16)r;
}

// ---------------------------------------------------------------------------
// fp32 -> bf16 elementwise convert (8 elems/thread).
// ---------------------------------------------------------------------------
__global__ __launch_bounds__(256) void cvt_f32_bf16(
    const float* __restrict__ in, u16* __restrict__ out)
{
    long i = ((long)blockIdx.x * 256 + threadIdx.x) * 8;
    float4 a = *(const float4*)(in + i);
    float4 b = *(const float4*)(in + i + 4);
    u16 v[8] = {f2bf(a.x), f2bf(a.y), f2bf(a.z), f2bf(a.w),
                f2bf(b.x), f2bf(b.y), f2bf(b.z), f2bf(b.w)};
    *(uint4*)(out + i) = *(uint4*)v;
}

// ---------------------------------------------------------------------------
// Transpose + downcast: in fp32 (R x C) -> out bf16 (C x R). 64x64 tiles.
// ---------------------------------------------------------------------------
__global__ __launch_bounds__(256) void transpose_f32_bf16(
    const float* __restrict__ in, u16* __restrict__ out, int R, int C)
{
    __shared__ u16 tile[64 * 72];
    const int c0 = blockIdx.x * 64, r0 = blockIdx.y * 64;
    const int t = threadIdx.x;
#pragma unroll
    for (int i = 0; i < 4; ++i) {
        int ch = i * 256 + t;
        int r = ch >> 4, c4 = (ch & 15) * 4;
        float4 v = *(const float4*)(in + (long)(r0 + r) * C + c0 + c4);
        tile[r * 72 + c4 + 0] = f2bf(v.x);
        tile[r * 72 + c4 + 1] = f2bf(v.y);
        tile[r * 72 + c4 + 2] = f2bf(v.z);
        tile[r * 72 + c4 + 3] = f2bf(v.w);
    }
    __syncthreads();
#pragma unroll
    for (int i = 0; i < 4; ++i) {
        int ch = i * 256 + t;
        int oc = ch >> 4, sg = (ch & 15) * 4;
        u16 vals[4];
#pragma unroll
        for (int j = 0; j < 4; ++j) vals[j] = tile[(sg + j) * 72 + oc];
        *(uint2*)(out + (long)(c0 + oc) * R + r0 + sg) = *(uint2*)vals;
    }
}

// ---------------------------------------------------------------------------
// 256x128-tile 8-wave GEMM, BK=64, mfma 16x16x32 bf16.
// TRIPLE-buffered LDS (3 x 48 KB): tile kt+2 burst-staged (6 global_load_lds)
// at P1 of kt; ONE vmcnt wait per K-tile (WAITV(6) at P2 retires tile kt+1)
// -> uniform 3-phase issue-to-wait distance; never drains in-flight stage.
// Wave grid 4x2 (wave tile 64x64): 16 ds_read_b128 / 32 MFMA per K-tile.
// 2 phases/K-tile (n-half each, 16 MFMA), 4 barriers/K-tile, setprio on MM.
// Staging: linear LDS dest, inverse-swizzled global source; reads XOR-swizzle
// byte ^= ((row&7)<<4). Grids: MODE1 768 blocks (3.0 rounds), MODE0 256 (1.0).
// MODE 0: fp32 row-major C. MODE 1: QKV epilogue (RoPE z<2, scatter; z==2
// writes V transposed (b,h,d,s)).
// ---------------------------------------------------------------------------
#define GLD16(gp, lp) __builtin_amdgcn_global_load_lds( \
    (const __attribute__((address_space(1))) u32*)(gp), \
    (__attribute__((address_space(3))) u32*)(lp), 16, 0, 0)
#define BAR() __builtin_amdgcn_s_barrier()
#define WAITV(n) asm volatile("s_waitcnt vmcnt(" #n ")" ::: "memory")

template <int MODE>
__global__ __launch_bounds__(512, 2) void gemm256(
    const u16* __restrict__ A, const u16* __restrict__ Bt,
    u16* __restrict__ OutB, float* __restrict__ OutF,
    const float* __restrict__ cosb, const float* __restrict__ sinb)
{
    extern __shared__ u16 sm[];   // 3 bufs x (A 16384 + B 8192 elems)
    const int t = threadIdx.x;
    const int w = t >> 6, l = t & 63;
    const int g = l >> 4, l15 = l & 15;
    const int wr = w >> 1, wc = w & 1;            // 4 x 2 wave grid

    const int NWG = (MODE == 1) ? 768 : 256;
    const int cpx = NWG / 8;                      // bijective XCD swizzle
    int bid = blockIdx.x;
    int wg = (bid & 7) * cpx + (bid >> 3);
    int z, m_t, n_t;
    if (MODE == 1) { z = wg >> 8; int rem = wg & 255; n_t = rem >> 4; m_t = rem & 15; }
    else           { z = 0; n_t = wg >> 4; m_t = wg & 15; }
    const int m0 = m_t * 256, n0 = n_t * 128;
    const u16* Ab = A + (long)m0 * 2048;
    const u16* Bb = Bt + (long)z * (2048L * 2048) + (long)n0 * 2048;

    // staging: each gld_lds inst covers 64 rows x 64 k (8 KB); thread t ->
    // row r0 = t>>3 (+64 per inst), physical k-chunk pk = t&7,
    // logical chunk = pk ^ (row&7) (inverse swizzle on global source).
    const int r0 = t >> 3;
    const int kk16 = (t & 7) ^ (r0 & 7);
    const long g_off = (long)r0 * 2048 + kk16 * 8;
    const int lds_l = w * 512;                    // + lane*16B implicit
    const int sw = (l15 & 7) << 3;                // read-side swizzle (elems)

#define STAGE(bufS_, ktS_) do { \
    const u16* _ga = Ab + (long)(ktS_) * 64 + g_off; \
    u16* _la = sm + (bufS_) * 24576 + lds_l; \
    GLD16(_ga,              _la); \
    GLD16(_ga +  64 * 2048, _la + 4096); \
    GLD16(_ga + 128 * 2048, _la + 8192); \
    GLD16(_ga + 192 * 2048, _la + 12288); \
    const u16* _gb = Bb + (long)(ktS_) * 64 + g_off; \
    u16* _lb = sm + (bufS_) * 24576 + 16384 + lds_l; \
    GLD16(_gb,              _lb); \
    GLD16(_gb + 64 * 2048,  _lb + 4096); \
} while (0)

    bf16x8 af[4][2], bfr[2][2];
    f32x4 acc[4][4] = {};

#define LDA_ALL(bufv) { const u16* _ba = sm + (bufv) * 24576; \
    _Pragma("unroll") for (int i = 0; i < 4; ++i) { \
        int row = wr * 64 + i * 16 + l15; \
        _Pragma("unroll") for (int kx = 0; kx < 2; ++kx) \
            af[i][kx] = *(const bf16x8*)(_ba + row * 64 + ((kx * 32 + g * 8) ^ sw)); } }

#define LDB_H(q, bufv) { const u16* _bb = sm + (bufv) * 24576 + 16384; \
    _Pragma("unroll") for (int j = 0; j < 2; ++j) { \
        int row = wc * 64 + (q) * 32 + j * 16 + l15; \
        _Pragma("unroll") for (int kx = 0; kx < 2; ++kx) \
            bfr[j][kx] = *(const bf16x8*)(_bb + row * 64 + ((kx * 32 + g * 8) ^ sw)); } }

#define MM(q) { __builtin_amdgcn_s_setprio(1); \
    _Pragma("unroll") for (int i = 0; i < 4; ++i) \
    _Pragma("unroll") for (int j = 0; j < 2; ++j) \
    _Pragma("unroll") for (int kx = 0; kx < 2; ++kx) \
        acc[i][(q) * 2 + j] = __builtin_amdgcn_mfma_f32_16x16x32_bf16( \
            af[i][kx], bfr[j][kx], acc[i][(q) * 2 + j], 0, 0, 0); \
    __builtin_amdgcn_s_setprio(0); }

    // prologue: stage tiles 0,1; retire tile 0 only (tile 1 stays in flight)
    STAGE(0, 0); STAGE(1, 1);
    WAITV(6); BAR();

    int buf = 0, bufS = 2;
#pragma unroll 1
    for (int kt = 0; kt < 32; ++kt) {
        const int ktS = (kt + 2 <= 31) ? (kt + 2) : 31;  // tail: restage 31
        // P1: read all A-frags + B n-half 0; burst-stage tile kt+2
        LDA_ALL(buf); LDB_H(0, buf);
        STAGE(bufS, ktS);
        BAR(); MM(0); BAR();
        // P2: read B n-half 1; retire tile kt+1 (issued 3 phases ago)
        LDB_H(1, buf);
        WAITV(6);
        BAR(); MM(1); BAR();
        buf  = (buf  == 2) ? 0 : buf + 1;
        bufS = (bufS == 2) ? 0 : bufS + 1;
    }

    // epilogue: C[row][col]: col = lane&15, row = (lane>>4)*4 + reg  [m89]
#pragma unroll
    for (int mt = 0; mt < 4; ++mt) {
#pragma unroll
        for (int nt = 0; nt < 4; ++nt) {
#pragma unroll
            for (int r = 0; r < 4; ++r) {
                int m = m0 + wr * 64 + mt * 16 + g * 4 + r;
                int n = n0 + wc * 64 + nt * 16 + l15;
                float v = acc[mt][nt][r];
                if (MODE == 0) {
                    OutF[(long)m * 2048 + n] = v;
                } else {
                    int b = m >> 11, s = m & 2047;
                    int h = n >> 7,  d = n & 127;
                    float pv = __shfl_xor(v, 1);
                    if (z < 2) {
                        int p = d >> 1;
                        float cc = cosb[s * 64 + p];
                        float ss = sinb[s * 64 + p];
                        v = ((d & 1) == 0) ? (v * cc - pv * ss) : (pv * ss + v * cc);
                    }
                    long zoff = (long)z * (NBATCH * NH * SEQ * HD);
                    if (z == 2)
                        OutB[zoff + ((long)(b * NH + h) * HD + d) * SEQ + s] = f2bf(v);
                    else
                        OutB[zoff + ((long)(b * NH + h) * SEQ + s) * HD + d] = f2bf(v);
                }
            }
        }
    }
#undef STAGE
#undef LDA_ALL
#undef LDB_H
#undef MM
}

// ---------------------------------------------------------------------------
// Flash attention with sliding window (unchanged from passing round).
// ---------------------------------------------------------------------------
__global__ __launch_bounds__(256, 2) void attn_kernel(
    const u16* __restrict__ Q,   // (B*H, S, HD)
    const u16* __restrict__ K,   // (B*H, S, HD)
    const u16* __restrict__ Vt,  // (B*H, HD, S)
    u16* __restrict__ Out)       // (B, S, D_MODEL)
{
    __shared__ u16 k_lds[64 * 136];
    __shared__ u16 vt_lds[128 * 72];
    __shared__ u16 p_lds[4 * 16 * 72];
    const int t = threadIdx.x, w = t >> 6, l = t & 63;
    const int g = l >> 4, l15 = l & 15;
    const int q0 = blockIdx.x * 64;
    const int bh = blockIdx.y;
    const int qbase = q0 + w * 16;
    const u16* Qb = Q + (long)bh * SEQ * HD;
    const u16* Kb = K + (long)bh * SEQ * HD;
    const u16* Vb = Vt + (long)bh * HD * SEQ;
    u16* pw = p_lds + w * 16 * 72;

    bf16x8 qf[4];
#pragma unroll
    for (int kk = 0; kk < 4; ++kk)
        qf[kk] = *(const bf16x8*)(Qb + (long)(qbase + l15) * HD + kk * 32 + g * 8);

    f32x4 of[8] = {};
    float mrow[4] = {-1e30f, -1e30f, -1e30f, -1e30f};
    float lrow[4] = {0.f, 0.f, 0.f, 0.f};
    const float scale = 0.088388347648318447f; // 1/sqrt(128)

    const int t0 = (q0 >= WINDOW) ? ((q0 - (WINDOW - 1)) >> 6) : 0;
    const int t1 = q0 >> 6;

    for (int kt = t0; kt <= t1; ++kt) {
        const int kv0 = kt * 64;
#pragma unroll
        for (int i = 0; i < 4; ++i) {
            int ch = i * 256 + t;
            { int r = ch >> 4, c = (ch & 15) * 8;
              *(uint4*)(k_lds + r * 136 + c) = *(const uint4*)(Kb + (long)(kv0 + r) * HD + c); }
            { int r = ch >> 3, c = (ch & 7) * 8;
              *(uint4*)(vt_lds + r * 72 + c) = *(const uint4*)(Vb + (long)r * SEQ + kv0 + c); }
        }
        __syncthreads();

        f32x4 sf[4] = {};
#pragma unroll
        for (int kk = 0; kk < 4; ++kk) {
#pragma unroll
            for (int nt = 0; nt < 4; ++nt) {
                bf16x8 kf = *(const bf16x8*)(k_lds + (nt * 16 + l15) * 136 + kk * 32 + g * 8);
                sf[nt] = __builtin_amdgcn_mfma_f32_16x16x32_bf16(qf[kk], kf, sf[nt], 0, 0, 0);
            }
        }
        const bool full = (kv0 + 63 <= qbase) && ((qbase + 15) - kv0 < WINDOW);
#pragma unroll
        for (int nt = 0; nt < 4; ++nt)
#pragma unroll
            for (int r = 0; r < 4; ++r) {
                float s = sf[nt][r] * scale;
                if (!full) {
                    int q = qbase + g * 4 + r;
                    int kv = kv0 + nt * 16 + l15;
                    bool ok = (kv <= q) && (q - kv < WINDOW);
                    s = ok ? s : -1e30f;
                }
                sf[nt][r] = s;
            }
        float fr[4];
#pragma unroll
        for (int r = 0; r < 4; ++r) {
            float v = fmaxf(fmaxf(sf[0][r], sf[1][r]), fmaxf(sf[2][r], sf[3][r]));
            v = fmaxf(v, __shfl_xor(v, 1));
            v = fmaxf(v, __shfl_xor(v, 2));
            v = fmaxf(v, __shfl_xor(v, 4));
            v = fmaxf(v, __shfl_xor(v, 8));
            float mn = fmaxf(mrow[r], v);
            fr[r] = __expf(mrow[r] - mn);
            mrow[r] = mn;
        }
        float rs[4] = {0.f, 0.f, 0.f, 0.f};
#pragma unroll
        for (int nt = 0; nt < 4; ++nt)
#pragma unroll
            for (int r = 0; r < 4; ++r) {
                float p = __expf(sf[nt][r] - mrow[r]);
                rs[r] += p;
                pw[(g * 4 + r) * 72 + nt * 16 + l15] = f2bf(p);
            }
#pragma unroll
        for (int r = 0; r < 4; ++r) {
            float v = rs[r];
            v += __shfl_xor(v, 1);
            v += __shfl_xor(v, 2);
            v += __shfl_xor(v, 4);
            v += __shfl_xor(v, 8);
            lrow[r] = lrow[r] * fr[r] + v;
        }
#pragma unroll
        for (int nd = 0; nd < 8; ++nd)
#pragma unroll
            for (int r = 0; r < 4; ++r) of[nd][r] *= fr[r];
#pragma unroll
        for (int kk = 0; kk < 2; ++kk) {
            bf16x8 pa = *(const bf16x8*)(pw + l15 * 72 + kk * 32 + g * 8);
#pragma unroll
            for (int nd = 0; nd < 8; ++nd) {
                bf16x8 vb = *(const bf16x8*)(vt_lds + (nd * 16 + l15) * 72 + kk * 32 + g * 8);
                of[nd] = __builtin_amdgcn_mfma_f32_16x16x32_bf16(pa, vb, of[nd], 0, 0, 0);
            }
        }
        __syncthreads();
    }
    const int b = bh >> 4, h = bh & 15;
#pragma unroll
    for (int r = 0; r < 4; ++r) {
        float inv = 1.0f / lrow[r];
        int q = qbase + g * 4 + r;
        u16* orow = Out + ((long)(b * SEQ + q)) * DMODEL + h * HD;
#pragma unroll
        for (int nd = 0; nd < 8; ++nd)
            orow[nd * 16 + l15] = f2bf(of[nd][r] * inv);
    }
}

// ---------------------------------------------------------------------------
extern "C" void kernel_launch(void* const* d_in, const int* in_sizes, int n_in,
                              void* d_out, int out_size, void* d_ws, size_t ws_size,
                              hipStream_t stream) {
    (void)in_sizes; (void)n_in; (void)out_size; (void)ws_size;
    const float* x    = (const float*)d_in[0];
    const float* fcos = (const float*)d_in[1];
    const float* fsin = (const float*)d_in[2];
    // d_in[3] = dense mask, unused (masking computed analytically)
    const float* wq = (const float*)d_in[4];
    const float* wk = (const float*)d_in[5];
    const float* wv = (const float*)d_in[6];
    const float* wo = (const float*)d_in[7];

    u16* ws = (u16*)d_ws;
    const long WT = 2048L * 2048;
    u16* xb  = ws;                        // 8388608
    u16* wtq = xb + 8388608L;
    u16* wtk = wtq + WT;
    u16* wtv = wtk + WT;
    u16* wto = wtv + WT;
    u16* qkv = wto + WT;                  // q:(b,h,s,d), k:(b,h,s,d), v:(b,h,d,s)
    u16* q_ws = qkv;
    u16* k_ws = qkv + 8388608L;
    u16* vt_ws = qkv + 16777216L;
    u16* attn_ws = qkv + 25165824L;

    hipFuncSetAttribute(reinterpret_cast<const void*>(gemm256<1>),
                        hipFuncAttributeMaxDynamicSharedMemorySize, 147456);
    hipFuncSetAttribute(reinterpret_cast<const void*>(gemm256<0>),
                        hipFuncAttributeMaxDynamicSharedMemorySize, 147456);

    dim3 blk(256);
    cvt_f32_bf16<<<4096, blk, 0, stream>>>(x, xb);
    transpose_f32_bf16<<<dim3(32, 32), blk, 0, stream>>>(wq, wtq, 2048, 2048);
    transpose_f32_bf16<<<dim3(32, 32), blk, 0, stream>>>(wk, wtk, 2048, 2048);
    transpose_f32_bf16<<<dim3(32, 32), blk, 0, stream>>>(wv, wtv, 2048, 2048);
    transpose_f32_bf16<<<dim3(32, 32), blk, 0, stream>>>(wo, wto, 2048, 2048);
    // QKV GEMM + RoPE; q,k -> (b,h,s,d); v -> (b,h,d,s)
    gemm256<1><<<768, 512, 147456, stream>>>(xb, wtq, qkv, nullptr, fcos, fsin);
    // flash attention -> (b, s, h*hd) bf16
    attn_kernel<<<dim3(32, 32), blk, 0, stream>>>(q_ws, k_ws, vt_ws, attn_ws);
    // out projection -> fp32 d_out
    gemm256<0><<<256, 512, 147456, stream>>>(attn_ws, wto, nullptr, (float*)d_out,
                                             nullptr, nullptr);
}

// Round 6
// 439.159 us; speedup vs baseline: 2.0531x; 1.0238x over previous
//
#include <hip/hip_runtime.h>
#include <hip/hip_bf16.h>

typedef __attribute__((ext_vector_type(8))) short bf16x8;
typedef __attribute__((ext_vector_type(4))) float f32x4;
typedef unsigned short u16;
typedef unsigned int u32;

#define SEQ 2048
#define DMODEL 2048
#define NH 16
#define HD 128
#define NBATCH 2
#define WINDOW 1024

__device__ __forceinline__ float bf2f(u16 v) {
    union { u32 u; float f; } x; x.u = ((u32)v) << 16; return x.f;
}
__device__ __forceinline__ u16 f2bf(float f) {
    union { float f; u32 u; } x; x.f = f;
    u32 u = x.u;
    u32 r = (u + 0x7fffu + ((u >> 16) & 1u)) >> 16;
    return (u16)r;
}

// ---------------------------------------------------------------------------
// fp32 -> bf16 elementwise convert (8 elems/thread).
// ---------------------------------------------------------------------------
__global__ __launch_bounds__(256) void cvt_f32_bf16(
    const float* __restrict__ in, u16* __restrict__ out)
{
    long i = ((long)blockIdx.x * 256 + threadIdx.x) * 8;
    float4 a = *(const float4*)(in + i);
    float4 b = *(const float4*)(in + i + 4);
    u16 v[8] = {f2bf(a.x), f2bf(a.y), f2bf(a.z), f2bf(a.w),
                f2bf(b.x), f2bf(b.y), f2bf(b.z), f2bf(b.w)};
    *(uint4*)(out + i) = *(uint4*)v;
}

// ---------------------------------------------------------------------------
// Transpose + downcast: in fp32 (R x C) -> out bf16 (C x R). 64x64 tiles.
// ---------------------------------------------------------------------------
__global__ __launch_bounds__(256) void transpose_f32_bf16(
    const float* __restrict__ in, u16* __restrict__ out, int R, int C)
{
    __shared__ u16 tile[64 * 72];
    const int c0 = blockIdx.x * 64, r0 = blockIdx.y * 64;
    const int t = threadIdx.x;
#pragma unroll
    for (int i = 0; i < 4; ++i) {
        int ch = i * 256 + t;
        int r = ch >> 4, c4 = (ch & 15) * 4;
        float4 v = *(const float4*)(in + (long)(r0 + r) * C + c0 + c4);
        tile[r * 72 + c4 + 0] = f2bf(v.x);
        tile[r * 72 + c4 + 1] = f2bf(v.y);
        tile[r * 72 + c4 + 2] = f2bf(v.z);
        tile[r * 72 + c4 + 3] = f2bf(v.w);
    }
    __syncthreads();
#pragma unroll
    for (int i = 0; i < 4; ++i) {
        int ch = i * 256 + t;
        int oc = ch >> 4, sg = (ch & 15) * 4;
        u16 vals[4];
#pragma unroll
        for (int j = 0; j < 4; ++j) vals[j] = tile[(sg + j) * 72 + oc];
        *(uint2*)(out + (long)(c0 + oc) * R + r0 + sg) = *(uint2*)vals;
    }
}

// ---------------------------------------------------------------------------
// 256x128-tile 8-wave GEMM, BK=64, mfma 16x16x32 bf16.
// FINE-PHASE schedule (T3/T4 + T5 on triple-buffered LDS):
//   per K-tile: 4 clusters of 8 MFMA; before cluster p, issue cluster p+1's
//   ds_reads (6/6/2/2) and 2 of the K-tile's 6 global_load_lds. ONE barrier
//   per K-tile with lgkmcnt(0) BEFORE it (closes cross-wave read-vs-restage
//   window); WAITV(6) retires next-buffer stages, keeps current 6 in flight.
//   sched_barrier(0) pins phase boundaries (rule #18). setprio around MFMA.
// Wave grid 4x2, wave tile 64x64. Grids: MODE1 768 (3.0 rounds), MODE0 256.
// Staging: linear LDS dest, inverse-swizzled global source; reads XOR-swizzle
// elem ^= (l15&7)<<3 (conflict-free both sides, involution).
// MODE 0: fp32 row-major C. MODE 1: QKV epilogue (RoPE z<2, scatter; z==2
// writes V transposed (b,h,d,s)).
// ---------------------------------------------------------------------------
#define GLD16(gp, lp) __builtin_amdgcn_global_load_lds( \
    (const __attribute__((address_space(1))) u32*)(gp), \
    (__attribute__((address_space(3))) u32*)(lp), 16, 0, 0)
#define BAR() __builtin_amdgcn_s_barrier()
#define WAITV(n) asm volatile("s_waitcnt vmcnt(" #n ")" ::: "memory")
#define LGKM0() asm volatile("s_waitcnt lgkmcnt(0)" ::: "memory")
#define SCHED0() __builtin_amdgcn_sched_barrier(0)

template <int MODE>
__global__ __launch_bounds__(512, 2) void gemm256(
    const u16* __restrict__ A, const u16* __restrict__ Bt,
    u16* __restrict__ OutB, float* __restrict__ OutF,
    const float* __restrict__ cosb, const float* __restrict__ sinb)
{
    extern __shared__ u16 sm[];   // 3 bufs x (A 16384 + B 8192 elems)
    const int t = threadIdx.x;
    const int w = t >> 6, l = t & 63;
    const int g = l >> 4, l15 = l & 15;
    const int wr = w >> 1, wc = w & 1;            // 4 x 2 wave grid

    const int NWG = (MODE == 1) ? 768 : 256;
    const int cpx = NWG / 8;                      // bijective XCD swizzle
    int bid = blockIdx.x;
    int wg = (bid & 7) * cpx + (bid >> 3);
    int z, m_t, n_t;
    if (MODE == 1) { z = wg >> 8; int rem = wg & 255; n_t = rem >> 4; m_t = rem & 15; }
    else           { z = 0; n_t = wg >> 4; m_t = wg & 15; }
    const int m0 = m_t * 256, n0 = n_t * 128;
    const u16* Ab = A + (long)m0 * 2048;
    const u16* Bb = Bt + (long)z * (2048L * 2048) + (long)n0 * 2048;

    // staging: each gld_lds covers 64 rows x 64 k (8 KB); thread t -> row
    // r0 = t>>3 (+64/inst), phys k-chunk pk = t&7, logical = pk ^ (row&7).
    const int r0 = t >> 3;
    const int kk16 = (t & 7) ^ (r0 & 7);
    const long g_off = (long)r0 * 2048 + kk16 * 8;
    const int lds_l = w * 512;
    const int sw = (l15 & 7) << 3;                // read-side swizzle (elems)

#define STAGE_A01(bufS_, ktS_) { const u16* _ga = Ab + (long)(ktS_) * 64 + g_off; \
    u16* _la = sm + (bufS_) * 24576 + lds_l; \
    GLD16(_ga, _la); GLD16(_ga + 64 * 2048, _la + 4096); }
#define STAGE_A23(bufS_, ktS_) { const u16* _ga = Ab + (long)(ktS_) * 64 + g_off; \
    u16* _la = sm + (bufS_) * 24576 + lds_l; \
    GLD16(_ga + 128 * 2048, _la + 8192); GLD16(_ga + 192 * 2048, _la + 12288); }
#define STAGE_B01(bufS_, ktS_) { const u16* _gb = Bb + (long)(ktS_) * 64 + g_off; \
    u16* _lb = sm + (bufS_) * 24576 + 16384 + lds_l; \
    GLD16(_gb, _lb); GLD16(_gb + 64 * 2048, _lb + 4096); }

    bf16x8 af_e[4], af_o[4], b_e[2], b_o[2];
    f32x4 acc[4][4] = {};

#define RD_A(dst, kx, bufv) { const u16* _ba = sm + (bufv) * 24576; \
    _Pragma("unroll") for (int i = 0; i < 4; ++i) { \
        int row = wr * 64 + i * 16 + l15; \
        dst[i] = *(const bf16x8*)(_ba + row * 64 + (((kx) * 32 + g * 8) ^ sw)); } }

#define RD_B(dst, kx, nh, bufv) { const u16* _bb = sm + (bufv) * 24576 + 16384; \
    _Pragma("unroll") for (int j = 0; j < 2; ++j) { \
        int row = wc * 64 + (nh) * 32 + j * 16 + l15; \
        dst[j] = *(const bf16x8*)(_bb + row * 64 + (((kx) * 32 + g * 8) ^ sw)); } }

#define MM8(afv, bv, nh) { __builtin_amdgcn_s_setprio(1); \
    _Pragma("unroll") for (int i = 0; i < 4; ++i) \
    _Pragma("unroll") for (int j = 0; j < 2; ++j) \
        acc[i][(nh) * 2 + j] = __builtin_amdgcn_mfma_f32_16x16x32_bf16( \
            afv[i], bv[j], acc[i][(nh) * 2 + j], 0, 0, 0); \
    __builtin_amdgcn_s_setprio(0); }

    // prologue: stage tiles 0,1; retire tile 0; preload P0 frags of tile 0
    STAGE_A01(0, 0); STAGE_A23(0, 0); STAGE_B01(0, 0);
    STAGE_A01(1, 1); STAGE_A23(1, 1); STAGE_B01(1, 1);
    WAITV(6); SCHED0(); BAR();
    RD_A(af_e, 0, 0); RD_B(b_e, 0, 0, 0);

    int buf = 0, bufS = 2;
#pragma unroll 1
    for (int kt = 0; kt < 32; ++kt) {
        const int ktS = (kt + 2 <= 31) ? (kt + 2) : 31;   // tail: dead restage
        const int bufN = (buf == 2) ? 0 : buf + 1;
        // P0: prefetch (kx1,nh0) frags; stage A rows 0-127 of tile kt+2
        RD_A(af_o, 1, buf); RD_B(b_o, 1, 0, buf);
        STAGE_A01(bufS, ktS);
        SCHED0();
        MM8(af_e, b_e, 0);
        SCHED0();
        // P1: prefetch (kx0,nh1); stage A rows 128-255
        RD_B(b_e, 0, 1, buf);
        STAGE_A23(bufS, ktS);
        SCHED0();
        MM8(af_o, b_o, 0);
        SCHED0();
        // P2: prefetch (kx1,nh1); stage B
        RD_B(b_o, 1, 1, buf);
        STAGE_B01(bufS, ktS);
        SCHED0();
        MM8(af_e, b_e, 1);
        SCHED0();
        // P3: drain reads of buf, retire next buffer's stages, barrier,
        //     prefetch next tile's P0 frags, last MFMA cluster (regs only)
        LGKM0(); SCHED0();
        WAITV(6); SCHED0();
        BAR();
        if (kt < 31) { RD_A(af_e, 0, bufN); RD_B(b_e, 0, 0, bufN); }
        SCHED0();
        MM8(af_o, b_o, 1);
        SCHED0();
        buf = bufN;
        bufS = (bufS == 2) ? 0 : bufS + 1;
    }
    WAITV(0);   // no DMA outlives the workgroup

    // epilogue: C[row][col]: col = lane&15, row = (lane>>4)*4 + reg  [m89]
#pragma unroll
    for (int mt = 0; mt < 4; ++mt) {
#pragma unroll
        for (int nt = 0; nt < 4; ++nt) {
#pragma unroll
            for (int r = 0; r < 4; ++r) {
                int m = m0 + wr * 64 + mt * 16 + g * 4 + r;
                int n = n0 + wc * 64 + nt * 16 + l15;
                float v = acc[mt][nt][r];
                if (MODE == 0) {
                    OutF[(long)m * 2048 + n] = v;
                } else {
                    int b = m >> 11, s = m & 2047;
                    int h = n >> 7,  d = n & 127;
                    float pv = __shfl_xor(v, 1);
                    if (z < 2) {
                        int p = d >> 1;
                        float cc = cosb[s * 64 + p];
                        float ss = sinb[s * 64 + p];
                        v = ((d & 1) == 0) ? (v * cc - pv * ss) : (pv * ss + v * cc);
                    }
                    long zoff = (long)z * (NBATCH * NH * SEQ * HD);
                    if (z == 2)
                        OutB[zoff + ((long)(b * NH + h) * HD + d) * SEQ + s] = f2bf(v);
                    else
                        OutB[zoff + ((long)(b * NH + h) * SEQ + s) * HD + d] = f2bf(v);
                }
            }
        }
    }
#undef STAGE_A01
#undef STAGE_A23
#undef STAGE_B01
#undef RD_A
#undef RD_B
#undef MM8
}

// ---------------------------------------------------------------------------
// Flash attention with sliding window (unchanged from passing round).
// ---------------------------------------------------------------------------
__global__ __launch_bounds__(256, 2) void attn_kernel(
    const u16* __restrict__ Q,   // (B*H, S, HD)
    const u16* __restrict__ K,   // (B*H, S, HD)
    const u16* __restrict__ Vt,  // (B*H, HD, S)
    u16* __restrict__ Out)       // (B, S, D_MODEL)
{
    __shared__ u16 k_lds[64 * 136];
    __shared__ u16 vt_lds[128 * 72];
    __shared__ u16 p_lds[4 * 16 * 72];
    const int t = threadIdx.x, w = t >> 6, l = t & 63;
    const int g = l >> 4, l15 = l & 15;
    const int q0 = blockIdx.x * 64;
    const int bh = blockIdx.y;
    const int qbase = q0 + w * 16;
    const u16* Qb = Q + (long)bh * SEQ * HD;
    const u16* Kb = K + (long)bh * SEQ * HD;
    const u16* Vb = Vt + (long)bh * HD * SEQ;
    u16* pw = p_lds + w * 16 * 72;

    bf16x8 qf[4];
#pragma unroll
    for (int kk = 0; kk < 4; ++kk)
        qf[kk] = *(const bf16x8*)(Qb + (long)(qbase + l15) * HD + kk * 32 + g * 8);

    f32x4 of[8] = {};
    float mrow[4] = {-1e30f, -1e30f, -1e30f, -1e30f};
    float lrow[4] = {0.f, 0.f, 0.f, 0.f};
    const float scale = 0.088388347648318447f; // 1/sqrt(128)

    const int t0 = (q0 >= WINDOW) ? ((q0 - (WINDOW - 1)) >> 6) : 0;
    const int t1 = q0 >> 6;

    for (int kt = t0; kt <= t1; ++kt) {
        const int kv0 = kt * 64;
#pragma unroll
        for (int i = 0; i < 4; ++i) {
            int ch = i * 256 + t;
            { int r = ch >> 4, c = (ch & 15) * 8;
              *(uint4*)(k_lds + r * 136 + c) = *(const uint4*)(Kb + (long)(kv0 + r) * HD + c); }
            { int r = ch >> 3, c = (ch & 7) * 8;
              *(uint4*)(vt_lds + r * 72 + c) = *(const uint4*)(Vb + (long)r * SEQ + kv0 + c); }
        }
        __syncthreads();

        f32x4 sf[4] = {};
#pragma unroll
        for (int kk = 0; kk < 4; ++kk) {
#pragma unroll
            for (int nt = 0; nt < 4; ++nt) {
                bf16x8 kf = *(const bf16x8*)(k_lds + (nt * 16 + l15) * 136 + kk * 32 + g * 8);
                sf[nt] = __builtin_amdgcn_mfma_f32_16x16x32_bf16(qf[kk], kf, sf[nt], 0, 0, 0);
            }
        }
        const bool full = (kv0 + 63 <= qbase) && ((qbase + 15) - kv0 < WINDOW);
#pragma unroll
        for (int nt = 0; nt < 4; ++nt)
#pragma unroll
            for (int r = 0; r < 4; ++r) {
                float s = sf[nt][r] * scale;
                if (!full) {
                    int q = qbase + g * 4 + r;
                    int kv = kv0 + nt * 16 + l15;
                    bool ok = (kv <= q) && (q - kv < WINDOW);
                    s = ok ? s : -1e30f;
                }
                sf[nt][r] = s;
            }
        float fr[4];
#pragma unroll
        for (int r = 0; r < 4; ++r) {
            float v = fmaxf(fmaxf(sf[0][r], sf[1][r]), fmaxf(sf[2][r], sf[3][r]));
            v = fmaxf(v, __shfl_xor(v, 1));
            v = fmaxf(v, __shfl_xor(v, 2));
            v = fmaxf(v, __shfl_xor(v, 4));
            v = fmaxf(v, __shfl_xor(v, 8));
            float mn = fmaxf(mrow[r], v);
            fr[r] = __expf(mrow[r] - mn);
            mrow[r] = mn;
        }
        float rs[4] = {0.f, 0.f, 0.f, 0.f};
#pragma unroll
        for (int nt = 0; nt < 4; ++nt)
#pragma unroll
            for (int r = 0; r < 4; ++r) {
                float p = __expf(sf[nt][r] - mrow[r]);
                rs[r] += p;
                pw[(g * 4 + r) * 72 + nt * 16 + l15] = f2bf(p);
            }
#pragma unroll
        for (int r = 0; r < 4; ++r) {
            float v = rs[r];
            v += __shfl_xor(v, 1);
            v += __shfl_xor(v, 2);
            v += __shfl_xor(v, 4);
            v += __shfl_xor(v, 8);
            lrow[r] = lrow[r] * fr[r] + v;
        }
#pragma unroll
        for (int nd = 0; nd < 8; ++nd)
#pragma unroll
            for (int r = 0; r < 4; ++r) of[nd][r] *= fr[r];
#pragma unroll
        for (int kk = 0; kk < 2; ++kk) {
            bf16x8 pa = *(const bf16x8*)(pw + l15 * 72 + kk * 32 + g * 8);
#pragma unroll
            for (int nd = 0; nd < 8; ++nd) {
                bf16x8 vb = *(const bf16x8*)(vt_lds + (nd * 16 + l15) * 72 + kk * 32 + g * 8);
                of[nd] = __builtin_amdgcn_mfma_f32_16x16x32_bf16(pa, vb, of[nd], 0, 0, 0);
            }
        }
        __syncthreads();
    }
    const int b = bh >> 4, h = bh & 15;
#pragma unroll
    for (int r = 0; r < 4; ++r) {
        float inv = 1.0f / lrow[r];
        int q = qbase + g * 4 + r;
        u16* orow = Out + ((long)(b * SEQ + q)) * DMODEL + h * HD;
#pragma unroll
        for (int nd = 0; nd < 8; ++nd)
            orow[nd * 16 + l15] = f2bf(of[nd][r] * inv);
    }
}

// ---------------------------------------------------------------------------
extern "C" void kernel_launch(void* const* d_in, const int* in_sizes, int n_in,
                              void* d_out, int out_size, void* d_ws, size_t ws_size,
                              hipStream_t stream) {
    (void)in_sizes; (void)n_in; (void)out_size; (void)ws_size;
    const float* x    = (const float*)d_in[0];
    const float* fcos = (const float*)d_in[1];
    const float* fsin = (const float*)d_in[2];
    // d_in[3] = dense mask, unused (masking computed analytically)
    const float* wq = (const float*)d_in[4];
    const float* wk = (const float*)d_in[5];
    const float* wv = (const float*)d_in[6];
    const float* wo = (const float*)d_in[7];

    u16* ws = (u16*)d_ws;
    const long WT = 2048L * 2048;
    u16* xb  = ws;                        // 8388608
    u16* wtq = xb + 8388608L;
    u16* wtk = wtq + WT;
    u16* wtv = wtk + WT;
    u16* wto = wtv + WT;
    u16* qkv = wto + WT;                  // q:(b,h,s,d), k:(b,h,s,d), v:(b,h,d,s)
    u16* q_ws = qkv;
    u16* k_ws = qkv + 8388608L;
    u16* vt_ws = qkv + 16777216L;
    u16* attn_ws = qkv + 25165824L;

    hipFuncSetAttribute(reinterpret_cast<const void*>(gemm256<1>),
                        hipFuncAttributeMaxDynamicSharedMemorySize, 147456);
    hipFuncSetAttribute(reinterpret_cast<const void*>(gemm256<0>),
                        hipFuncAttributeMaxDynamicSharedMemorySize, 147456);

    dim3 blk(256);
    cvt_f32_bf16<<<4096, blk, 0, stream>>>(x, xb);
    transpose_f32_bf16<<<dim3(32, 32), blk, 0, stream>>>(wq, wtq, 2048, 2048);
    transpose_f32_bf16<<<dim3(32, 32), blk, 0, stream>>>(wk, wtk, 2048, 2048);
    transpose_f32_bf16<<<dim3(32, 32), blk, 0, stream>>>(wv, wtv, 2048, 2048);
    transpose_f32_bf16<<<dim3(32, 32), blk, 0, stream>>>(wo, wto, 2048, 2048);
    // QKV GEMM + RoPE; q,k -> (b,h,s,d); v -> (b,h,d,s)
    gemm256<1><<<768, 512, 147456, stream>>>(xb, wtq, qkv, nullptr, fcos, fsin);
    // flash attention -> (b, s, h*hd) bf16
    attn_kernel<<<dim3(32, 32), blk, 0, stream>>>(q_ws, k_ws, vt_ws, attn_ws);
    // out projection -> fp32 d_out
    gemm256<0><<<256, 512, 147456, stream>>>(attn_ws, wto, nullptr, (float*)d_out,
                                             nullptr, nullptr);
}